// Round 9
// baseline (1208.247 us; speedup 1.0000x reference)
//
#include <hip/hip_runtime.h>
#include <cstdint>

#define UNITS 128
#define GATES 512            // 4*UNITS
#define IN_DIM 128
#define BATCH 64
#define SEQ 2048
#define ROWS (BATCH * SEQ)   // 131072

typedef _Float16 f16;
typedef _Float16 f16x2 __attribute__((ext_vector_type(2)));
typedef _Float16 f16x4 __attribute__((ext_vector_type(4)));
typedef _Float16 f16x8 __attribute__((ext_vector_type(8)));
typedef float    f32x4 __attribute__((ext_vector_type(4)));

static __device__ __forceinline__ float sigmoid_f(float x) {
    float e = __builtin_amdgcn_exp2f(-1.44269504f * x);
    return __builtin_amdgcn_rcpf(1.0f + e);
}
static __device__ __forceinline__ float tanh_f(float x) {
    float e = __builtin_amdgcn_exp2f(2.8853900817779268f * x);
    return 1.0f - 2.0f * __builtin_amdgcn_rcpf(1.0f + e);
}

// v_dot4_i32_i8: 4 signed-i8 MACs into i32 per instruction.
static __device__ __forceinline__ int dot4(int a, int b, int c) {
#if __has_builtin(__builtin_amdgcn_sdot4)
    return __builtin_amdgcn_sdot4(a, b, c, false);
#else
    asm volatile("v_dot4_i32_i8 %0, %1, %2, %0" : "+v"(c) : "v"(a), "v"(b));
    return c;
#endif
}

// Workgroup barrier that orders LDS only: skips __syncthreads()'s
// s_waitcnt vmcnt(0), so xp prefetch and out[] stores stay in flight.
static __device__ __forceinline__ void lds_barrier() {
    __asm__ volatile("s_waitcnt lgkmcnt(0)\n\ts_barrier" ::: "memory");
}

// ---------------------------------------------------------------------------
// Kernel 1: WxT[n][k] = (f16)Wx[k][n]  — f32 coalesced read, f16 transpose out
// ---------------------------------------------------------------------------
__global__ void wxt_kernel(const float* __restrict__ W,
                           f16* __restrict__ WxT) {
    int idx = blockIdx.x * 256 + threadIdx.x;     // 0 .. 65535 over Wx (128x512)
    int k = idx >> 9, n = idx & 511;              // coalesced read of W[idx]
    WxT[n * IN_DIM + k] = (f16)W[idx];
}

// ---------------------------------------------------------------------------
// Kernel 2: xp = data @ Wx + b, f16, TRANSPOSED layout xp[b][col][t]
// (R4/R7-verified)
// ---------------------------------------------------------------------------
__global__ __launch_bounds__(256) void xp_gemm(
        const float* __restrict__ A,      // data f32, ROWS x 128
        const f16*  __restrict__ WxT,     // 512 x 128 f16
        const float* __restrict__ bias,   // 512 f32
        f16* __restrict__ xp) {           // [64][512][2048] f16
    const int wave = threadIdx.x >> 6;
    const int lane = threadIdx.x & 63;
    const int m16  = lane & 15;
    const int q    = lane >> 4;
    const int rowBase = blockIdx.x * 128 + wave * 32;   // 128 | 2048: one sample
    const int bidx = rowBase >> 11;                     // sample index
    const int tBase = (rowBase & 2047) + q * 4;

    f16x8 a[2][4];
    #pragma unroll
    for (int mc = 0; mc < 2; ++mc)
        #pragma unroll
        for (int ks = 0; ks < 4; ++ks) {
            const float* p = A + (size_t)(rowBase + mc * 16 + m16) * IN_DIM
                               + ks * 32 + q * 8;
            float4 lo = *(const float4*)p;
            float4 hi = *(const float4*)(p + 4);
            f16x8 v;
            v[0] = (f16)lo.x; v[1] = (f16)lo.y; v[2] = (f16)lo.z; v[3] = (f16)lo.w;
            v[4] = (f16)hi.x; v[5] = (f16)hi.y; v[6] = (f16)hi.z; v[7] = (f16)hi.w;
            a[mc][ks] = v;
        }

    for (int nt = 0; nt < 32; ++nt) {
        f16x8 bfr[4];
        #pragma unroll
        for (int ks = 0; ks < 4; ++ks)
            bfr[ks] = *(const f16x8*)(WxT + (nt * 16 + m16) * IN_DIM + ks * 32 + q * 8);
        f32x4 acc0 = {0.f, 0.f, 0.f, 0.f}, acc1 = {0.f, 0.f, 0.f, 0.f};
        #pragma unroll
        for (int ks = 0; ks < 4; ++ks) {
            acc0 = __builtin_amdgcn_mfma_f32_16x16x32_f16(a[0][ks], bfr[ks], acc0, 0, 0, 0);
            acc1 = __builtin_amdgcn_mfma_f32_16x16x32_f16(a[1][ks], bfr[ks], acc1, 0, 0, 0);
        }
        const int col = nt * 16 + m16;
        float bv = bias[col];
        f16x4 v0, v1;
        #pragma unroll
        for (int r = 0; r < 4; ++r) {
            v0[r] = (f16)(acc0[r] + bv);
            v1[r] = (f16)(acc1[r] + bv);
        }
        f16* dst = xp + ((size_t)bidx * GATES + col) * SEQ + tBase;
        *(f16x4*)(dst)      = v0;        // rows rowBase+q*4+r      -> t, t+1..t+3
        *(f16x4*)(dst + 16) = v1;        // rows rowBase+16+q*4+r   -> t+16..
    }
}

// ---------------------------------------------------------------------------
// Kernel 3 (v8): i8-dot4 scan, 128 threads (2 waves), ALL 4 GATES PER LANE.
//
// R8 left step = 954 cy (424 issue busy, ~530 stall) at 4 waves x 2 cols/
// lane. The 2-cols split forces: 2 gate shuffles + 4 cndmasks + redundant
// both-halves compute + 4-wave barrier skew + per-step out addressing.
// New layout: lane j owns cell j's FULL column set {j, j+128, j+256, j+384}
// (i,f,o,g) -> gates combine lane-locally: NO shuffles, NO cndmasks, single
// straight tail. 2-wave barrier. Dots: 128 dot4/lane (512 cy issue/wave) —
// raises SIMD utilization instead of wall time (ring was stall-dominated).
//   * out[] stores batched per 8-step window into the NEXT window's
//     post-barrier LDS-wait shadow (hout[8] registers).
//   * h->i8 fused: h127 = fma(-254*so, rc, 127*so); out value = h127/127.
//   * wq = 128 VGPRs, hb = 32, xp pipeline = 48 -> ~240 VGPR, fits.
// PRE-COMMITTED: scan >= 814 µs -> revert to R8, declare ceiling.
// ---------------------------------------------------------------------------
__global__ __launch_bounds__(128, 1) void lstm_scan_v8(
        const float* __restrict__ W,      // 256 x 512 f32 (rows 128.. = Wh)
        const f16* __restrict__ xpt,      // [64][512][2048] f16
        float* __restrict__ out) {        // ROWS x 128 f32
    __shared__ __align__(16) signed char hq[2][UNITS];   // 256 B

    const int j = threadIdx.x;            // cell, 0..127
    const int b = blockIdx.x;

    // ---- per-column i8 quantization of Wh (init only; W is 512 KiB, L2-hot)
    float msI, msF, msO, msG;
    uint32_t wqI[32], wqF[32], wqO[32], wqG[32];
#define QCOL(ARR, MS, COL)                                                    \
    {                                                                         \
        const int col_ = (COL);                                               \
        float mx_ = 1e-20f;                                                   \
        for (int k_ = 0; k_ < 128; ++k_)                                      \
            mx_ = fmaxf(mx_, fabsf(W[(size_t)(IN_DIM + k_) * GATES + col_]));  \
        const float inv_ = 127.f / mx_;                                       \
        MS = mx_ * (1.f / (127.f * 127.f));                                   \
        _Pragma("unroll")                                                     \
        for (int d_ = 0; d_ < 32; ++d_) {                                     \
            uint32_t p_ = 0;                                                  \
            _Pragma("unroll")                                                 \
            for (int t_ = 0; t_ < 4; ++t_) {                                  \
                int q_ = (int)rintf(                                          \
                    W[(size_t)(IN_DIM + 4 * d_ + t_) * GATES + col_] * inv_); \
                p_ |= (uint32_t)(q_ & 255) << (8 * t_);                       \
            }                                                                 \
            ARR[d_] = p_;                                                     \
        }                                                                     \
    }
    QCOL(wqI, msI, j)
    QCOL(wqF, msF, j + 128)
    QCOL(wqO, msO, j + 256)
    QCOL(wqG, msG, j + 384)
#undef QCOL

    float cc = 1.0f;                      // reference: c0 = ones
    hq[0][j] = 0;                         // h0 = zeros (128 threads = 128 cells)

    // xp column streams for the 4 gates, 8 timesteps per 16B load
    const f16* xI = xpt + ((size_t)b * GATES + j      ) * SEQ;
    const f16* xF = xpt + ((size_t)b * GATES + j + 128) * SEQ;
    const f16* xO = xpt + ((size_t)b * GATES + j + 256) * SEQ;
    const f16* xG = xpt + ((size_t)b * GATES + j + 384) * SEQ;
    f16x8 xcI = *(const f16x8*)xI,       xcF = *(const f16x8*)xF;
    f16x8 xcO = *(const f16x8*)xO,       xcG = *(const f16x8*)xG;
    f16x8 xnI = *(const f16x8*)(xI + 8), xnF = *(const f16x8*)(xF + 8);
    f16x8 xnO = *(const f16x8*)(xO + 8), xnG = *(const f16x8*)(xG + 8);
    __syncthreads();                      // once, before the loop

    float hout[8];
    for (int w = 0; w < SEQ / 8; ++w) {
        // prefetch window w+2 (clamped)
        const int wn = (w + 2 < SEQ / 8) ? (w + 2) : (SEQ / 8 - 1);
        f16x8 xpI = *(const f16x8*)(xI + (size_t)wn * 8);
        f16x8 xpF = *(const f16x8*)(xF + (size_t)wn * 8);
        f16x8 xpO = *(const f16x8*)(xO + (size_t)wn * 8);
        f16x8 xpG = *(const f16x8*)(xG + (size_t)wn * 8);

        // previous window's out[] stores: issued in the post-barrier shadow
        if (w > 0) {
            float* ob = out + ((size_t)b * SEQ + (size_t)(w - 1) * 8) * UNITS + j;
            #pragma unroll
            for (int u = 0; u < 8; ++u) ob[u * UNITS] = hout[u];
        }

        #pragma unroll
        for (int u = 0; u < 8; ++u) {
            const int cur = u & 1, nxt = cur ^ 1;   // w*8 even -> t&1 == u&1

            // h broadcast: 8 x 16B LDS reads (128 i8), same address all lanes
            const uint4* hsrc = (const uint4*)(&hq[cur][0]);
            uint4 hb[8];
            #pragma unroll
            for (int i = 0; i < 8; ++i) hb[i] = hsrc[i];

            // 128 v_dot4_i32_i8: 4 chains (one per gate), exact i32 accum
            int aI = 0, aF = 0, aO = 0, aG = 0;
            #pragma unroll
            for (int i = 0; i < 8; ++i) {
                const int d0 = (int)hb[i].x;
                const int d1 = (int)hb[i].y;
                const int d2 = (int)hb[i].z;
                const int d3 = (int)hb[i].w;
                const int k = 4 * i;
                aI = dot4(d0, wqI[k],     aI);
                aF = dot4(d0, wqF[k],     aF);
                aO = dot4(d0, wqO[k],     aO);
                aG = dot4(d0, wqG[k],     aG);
                aI = dot4(d1, wqI[k + 1], aI);
                aF = dot4(d1, wqF[k + 1], aF);
                aO = dot4(d1, wqO[k + 1], aO);
                aG = dot4(d1, wqG[k + 1], aG);
                aI = dot4(d2, wqI[k + 2], aI);
                aF = dot4(d2, wqF[k + 2], aF);
                aO = dot4(d2, wqO[k + 2], aO);
                aG = dot4(d2, wqG[k + 2], aG);
                aI = dot4(d3, wqI[k + 3], aI);
                aF = dot4(d3, wqF[k + 3], aF);
                aO = dot4(d3, wqO[k + 3], aO);
                aG = dot4(d3, wqG[k + 3], aG);
            }
            float zI = fmaf((float)aI, msI, (float)xcI[u]);
            float zF = fmaf((float)aF, msF, (float)xcF[u]);
            float zO = fmaf((float)aO, msO, (float)xcO[u]);
            float zG = fmaf((float)aG, msG, (float)xcG[u]);

            // all 4 gates lane-local: no shuffles, no selects
            float si = sigmoid_f(zI);
            float sf = sigmoid_f(zF);
            float so = sigmoid_f(zO);
            float eg = __builtin_amdgcn_exp2f(2.8853900817779268f * zG);
            float tg = 1.f - 2.f * __builtin_amdgcn_rcpf(1.f + eg);

            cc = sf * cc + si * tg;
            // h*127 fused: h = so*tanh(cc); tanh = 1-2*rc
            float ec = __builtin_amdgcn_exp2f(2.8853900817779268f * cc);
            float rc = __builtin_amdgcn_rcpf(1.f + ec);
            float h127 = fmaf(-254.f * so, rc, 127.f * so);
            // |h| < 1 strictly -> rint in [-127,127], no clamp
            hq[nxt][j] = (signed char)(int)rintf(h127);
            hout[u] = h127 * 7.874015748031496e-3f;   // h = h127/127, off-path
            lds_barrier();   // LDS-only ordering: loads/stores stay in flight
        }
        xcI = xnI; xcF = xnF; xcO = xnO; xcG = xnG;
        xnI = xpI; xnF = xpF; xnO = xpO; xnG = xpG;
    }
    {   // final window's out[] stores
        float* ob = out + ((size_t)b * SEQ + (size_t)(SEQ / 8 - 1) * 8) * UNITS + j;
        #pragma unroll
        for (int u = 0; u < 8; ++u) ob[u * UNITS] = hout[u];
    }
}

// ---------------------------------------------------------------------------
// Fallback (workspace too small): fused 4-wave scan, weights register-resident.
// ---------------------------------------------------------------------------
__global__ __launch_bounds__(256, 1) void lstm_scan_fused(
        const float* __restrict__ W,      // 256 x 512 f32
        const float* __restrict__ bias,   // 512 f32
        const float* __restrict__ data,   // ROWS x 128 f32
        float* __restrict__ out) {        // ROWS x 128 f32
    __shared__ __align__(16) f16 h_lds[2][UNITS];
    __shared__ __align__(16) f16 x_lds[2][UNITS];

    const int tid  = threadIdx.x;
    const int b    = blockIdx.x;
    const int wave = tid >> 6;
    const int lane = tid & 63;
    const int half = lane >> 5;
    const int cell = wave * 32 + (lane & 31);
    const int c0   = cell + half * 256;
    const int c1   = c0 + 128;

    f16x2 wh0[64], wh1[64];
    #pragma unroll
    for (int k = 0; k < 64; ++k) {
        wh0[k] = f16x2{(f16)W[(size_t)(IN_DIM + 2 * k) * GATES + c0],
                       (f16)W[(size_t)(IN_DIM + 2 * k + 1) * GATES + c0]};
        wh1[k] = f16x2{(f16)W[(size_t)(IN_DIM + 2 * k) * GATES + c1],
                       (f16)W[(size_t)(IN_DIM + 2 * k + 1) * GATES + c1]};
    }
    f16x2 wxa[64], wxb[64];
    #pragma unroll
    for (int k = 0; k < 64; ++k) {
        wxa[k] = f16x2{(f16)W[(size_t)(2 * k) * GATES + c0],
                       (f16)W[(size_t)(2 * k + 1) * GATES + c0]};
        wxb[k] = f16x2{(f16)W[(size_t)(2 * k) * GATES + c1],
                       (f16)W[(size_t)(2 * k + 1) * GATES + c1]};
    }
    float bb0 = bias[c0];
    float bb1 = bias[c1];

    float c = 1.0f;
    if (tid < UNITS) h_lds[0][tid] = (f16)0.f;
    if (tid < UNITS)
        x_lds[0][tid] = (f16)data[(size_t)b * SEQ * IN_DIM + tid];
    __syncthreads();

    for (int t = 0; t < SEQ; ++t) {
        const int cur = t & 1, nxt = cur ^ 1;
        float a00 = bb0, a01 = 0.f, a10 = bb1, a11 = 0.f;

        {
            const uint4* xsrc = (const uint4*)(&x_lds[cur][0]);
            uint4 xb[16];
            #pragma unroll
            for (int i = 0; i < 16; ++i) xb[i] = xsrc[i];
            #pragma unroll
            for (int i = 0; i < 16; ++i) {
                f16x2 p0 = __builtin_bit_cast(f16x2, xb[i].x);
                f16x2 p1 = __builtin_bit_cast(f16x2, xb[i].y);
                f16x2 p2 = __builtin_bit_cast(f16x2, xb[i].z);
                f16x2 p3 = __builtin_bit_cast(f16x2, xb[i].w);
                const int k = 4 * i;
                if (i < 8) {
                    a00 = __builtin_amdgcn_fdot2(p0, wxa[k],     a00, false);
                    a10 = __builtin_amdgcn_fdot2(p0, wxb[k],     a10, false);
                    a00 = __builtin_amdgcn_fdot2(p1, wxa[k + 1], a00, false);
                    a10 = __builtin_amdgcn_fdot2(p1, wxb[k + 1], a10, false);
                    a00 = __builtin_amdgcn_fdot2(p2, wxa[k + 2], a00, false);
                    a10 = __builtin_amdgcn_fdot2(p2, wxb[k + 2], a10, false);
                    a00 = __builtin_amdgcn_fdot2(p3, wxa[k + 3], a00, false);
                    a10 = __builtin_amdgcn_fdot2(p3, wxb[k + 3], a10, false);
                } else {
                    a01 = __builtin_amdgcn_fdot2(p0, wxa[k],     a01, false);
                    a11 = __builtin_amdgcn_fdot2(p0, wxb[k],     a11, false);
                    a01 = __builtin_amdgcn_fdot2(p1, wxa[k + 1], a01, false);
                    a11 = __builtin_amdgcn_fdot2(p1, wxb[k + 1], a11, false);
                    a01 = __builtin_amdgcn_fdot2(p2, wxa[k + 2], a01, false);
                    a11 = __builtin_amdgcn_fdot2(p2, wxb[k + 2], a11, false);
                    a01 = __builtin_amdgcn_fdot2(p3, wxa[k + 3], a01, false);
                    a11 = __builtin_amdgcn_fdot2(p3, wxb[k + 3], a11, false);
                }
            }
        }
        {
            const uint4* hsrc = (const uint4*)(&h_lds[cur][0]);
            uint4 hb[16];
            #pragma unroll
            for (int i = 0; i < 16; ++i) hb[i] = hsrc[i];
            #pragma unroll
            for (int i = 0; i < 16; ++i) {
                f16x2 p0 = __builtin_bit_cast(f16x2, hb[i].x);
                f16x2 p1 = __builtin_bit_cast(f16x2, hb[i].y);
                f16x2 p2 = __builtin_bit_cast(f16x2, hb[i].z);
                f16x2 p3 = __builtin_bit_cast(f16x2, hb[i].w);
                const int k = 4 * i;
                if (i < 8) {
                    a00 = __builtin_amdgcn_fdot2(p0, wh0[k],     a00, false);
                    a10 = __builtin_amdgcn_fdot2(p0, wh1[k],     a10, false);
                    a00 = __builtin_amdgcn_fdot2(p1, wh0[k + 1], a00, false);
                    a10 = __builtin_amdgcn_fdot2(p1, wh1[k + 1], a10, false);
                    a00 = __builtin_amdgcn_fdot2(p2, wh0[k + 2], a00, false);
                    a10 = __builtin_amdgcn_fdot2(p2, wh1[k + 2], a10, false);
                    a00 = __builtin_amdgcn_fdot2(p3, wh0[k + 3], a00, false);
                    a10 = __builtin_amdgcn_fdot2(p3, wh1[k + 3], a10, false);
                } else {
                    a01 = __builtin_amdgcn_fdot2(p0, wh0[k],     a01, false);
                    a11 = __builtin_amdgcn_fdot2(p0, wh1[k],     a11, false);
                    a01 = __builtin_amdgcn_fdot2(p1, wh0[k + 1], a01, false);
                    a11 = __builtin_amdgcn_fdot2(p1, wh1[k + 1], a11, false);
                    a01 = __builtin_amdgcn_fdot2(p2, wh0[k + 2], a01, false);
                    a11 = __builtin_amdgcn_fdot2(p2, wh1[k + 2], a11, false);
                    a01 = __builtin_amdgcn_fdot2(p3, wh0[k + 3], a01, false);
                    a11 = __builtin_amdgcn_fdot2(p3, wh1[k + 3], a11, false);
                }
            }
        }
        float z0 = a00 + a01, z1 = a10 + a11;

        float s0 = sigmoid_f(z0);
        float s1 = (half == 0) ? sigmoid_f(z1) : tanh_f(z1);
        float p0 = __shfl_xor(s0, 32, 64);
        float p1 = __shfl_xor(s1, 32, 64);

        if (half == 0) {
            c = s1 * c + s0 * p1;
            float h = p0 * tanh_f(c);
            h_lds[nxt][cell] = (f16)h;
            out[((size_t)b * SEQ + t) * UNITS + cell] = h;
        }
        if (tid < UNITS) {
            int t1 = (t + 1 < SEQ) ? (t + 1) : t;
            x_lds[nxt][tid] = (f16)data[(size_t)b * SEQ * IN_DIM
                                        + (size_t)t1 * IN_DIM + tid];
        }
        lds_barrier();
    }
}

// ---------------------------------------------------------------------------
extern "C" void kernel_launch(void* const* d_in, const int* in_sizes, int n_in,
                              void* d_out, int out_size, void* d_ws, size_t ws_size,
                              hipStream_t stream) {
    const float* data = (const float*)d_in[0];   // f32 (64,2048,128)
    const float* W    = (const float*)d_in[1];   // f32 (256,512)
    const float* bias = (const float*)d_in[2];   // f32 (512,)
    float* out = (float*)d_out;                  // f32 (64,2048,128)

    const size_t wxt_bytes = (size_t)GATES * IN_DIM * sizeof(f16);  // 128 KiB
    const size_t xp_bytes  = (size_t)ROWS * GATES * sizeof(f16);    // 128 MiB
    if (ws_size >= wxt_bytes + xp_bytes) {
        f16* WxT = (f16*)d_ws;
        f16* xp  = (f16*)((char*)d_ws + wxt_bytes);
        hipLaunchKernelGGL(wxt_kernel, dim3(256), dim3(256), 0, stream, W, WxT);
        hipLaunchKernelGGL(xp_gemm, dim3(ROWS / 128), dim3(256), 0, stream,
                           data, WxT, bias, xp);
        hipLaunchKernelGGL(lstm_scan_v8, dim3(BATCH), dim3(128), 0, stream,
                           W, xp, out);
    } else {
        // Workspace too small: fused fallback (all weights register-resident).
        hipLaunchKernelGGL(lstm_scan_fused, dim3(BATCH), dim3(256), 0, stream,
                           W, bias, data, out);
    }
}

// Round 10
// 982.622 us; speedup vs baseline: 1.2296x; 1.2296x over previous
//
#include <hip/hip_runtime.h>
#include <cstdint>

#define UNITS 128
#define GATES 512            // 4*UNITS
#define IN_DIM 128
#define BATCH 64
#define SEQ 2048
#define ROWS (BATCH * SEQ)   // 131072

typedef _Float16 f16;
typedef _Float16 f16x2 __attribute__((ext_vector_type(2)));
typedef _Float16 f16x4 __attribute__((ext_vector_type(4)));
typedef _Float16 f16x8 __attribute__((ext_vector_type(8)));
typedef float    f32x4 __attribute__((ext_vector_type(4)));

static __device__ __forceinline__ float sigmoid_f(float x) {
    float e = __builtin_amdgcn_exp2f(-1.44269504f * x);
    return __builtin_amdgcn_rcpf(1.0f + e);
}
static __device__ __forceinline__ float tanh_f(float x) {
    float e = __builtin_amdgcn_exp2f(2.8853900817779268f * x);
    return 1.0f - 2.0f * __builtin_amdgcn_rcpf(1.0f + e);
}

// v_dot4_i32_i8: 4 signed-i8 MACs into i32 per instruction.
static __device__ __forceinline__ int dot4(int a, int b, int c) {
#if __has_builtin(__builtin_amdgcn_sdot4)
    return __builtin_amdgcn_sdot4(a, b, c, false);
#else
    asm volatile("v_dot4_i32_i8 %0, %1, %2, %0" : "+v"(c) : "v"(a), "v"(b));
    return c;
#endif
}

// Workgroup barrier that orders LDS only: skips __syncthreads()'s
// s_waitcnt vmcnt(0), so xp prefetch and out[] stores stay in flight.
static __device__ __forceinline__ void lds_barrier() {
    __asm__ volatile("s_waitcnt lgkmcnt(0)\n\ts_barrier" ::: "memory");
}

// ---------------------------------------------------------------------------
// Kernel 1: WxT[n][k] = (f16)Wx[k][n]  — f32 coalesced read, f16 transpose out
// ---------------------------------------------------------------------------
__global__ void wxt_kernel(const float* __restrict__ W,
                           f16* __restrict__ WxT) {
    int idx = blockIdx.x * 256 + threadIdx.x;     // 0 .. 65535 over Wx (128x512)
    int k = idx >> 9, n = idx & 511;              // coalesced read of W[idx]
    WxT[n * IN_DIM + k] = (f16)W[idx];
}

// ---------------------------------------------------------------------------
// Kernel 2: xp = data @ Wx + b, f16, TRANSPOSED layout xp[b][col][t]
// (R4/R7-verified)
// ---------------------------------------------------------------------------
__global__ __launch_bounds__(256) void xp_gemm(
        const float* __restrict__ A,      // data f32, ROWS x 128
        const f16*  __restrict__ WxT,     // 512 x 128 f16
        const float* __restrict__ bias,   // 512 f32
        f16* __restrict__ xp) {           // [64][512][2048] f16
    const int wave = threadIdx.x >> 6;
    const int lane = threadIdx.x & 63;
    const int m16  = lane & 15;
    const int q    = lane >> 4;
    const int rowBase = blockIdx.x * 128 + wave * 32;   // 128 | 2048: one sample
    const int bidx = rowBase >> 11;                     // sample index
    const int tBase = (rowBase & 2047) + q * 4;

    f16x8 a[2][4];
    #pragma unroll
    for (int mc = 0; mc < 2; ++mc)
        #pragma unroll
        for (int ks = 0; ks < 4; ++ks) {
            const float* p = A + (size_t)(rowBase + mc * 16 + m16) * IN_DIM
                               + ks * 32 + q * 8;
            float4 lo = *(const float4*)p;
            float4 hi = *(const float4*)(p + 4);
            f16x8 v;
            v[0] = (f16)lo.x; v[1] = (f16)lo.y; v[2] = (f16)lo.z; v[3] = (f16)lo.w;
            v[4] = (f16)hi.x; v[5] = (f16)hi.y; v[6] = (f16)hi.z; v[7] = (f16)hi.w;
            a[mc][ks] = v;
        }

    for (int nt = 0; nt < 32; ++nt) {
        f16x8 bfr[4];
        #pragma unroll
        for (int ks = 0; ks < 4; ++ks)
            bfr[ks] = *(const f16x8*)(WxT + (nt * 16 + m16) * IN_DIM + ks * 32 + q * 8);
        f32x4 acc0 = {0.f, 0.f, 0.f, 0.f}, acc1 = {0.f, 0.f, 0.f, 0.f};
        #pragma unroll
        for (int ks = 0; ks < 4; ++ks) {
            acc0 = __builtin_amdgcn_mfma_f32_16x16x32_f16(a[0][ks], bfr[ks], acc0, 0, 0, 0);
            acc1 = __builtin_amdgcn_mfma_f32_16x16x32_f16(a[1][ks], bfr[ks], acc1, 0, 0, 0);
        }
        const int col = nt * 16 + m16;
        float bv = bias[col];
        f16x4 v0, v1;
        #pragma unroll
        for (int r = 0; r < 4; ++r) {
            v0[r] = (f16)(acc0[r] + bv);
            v1[r] = (f16)(acc1[r] + bv);
        }
        f16* dst = xp + ((size_t)bidx * GATES + col) * SEQ + tBase;
        *(f16x4*)(dst)      = v0;        // rows rowBase+q*4+r      -> t, t+1..t+3
        *(f16x4*)(dst + 16) = v1;        // rows rowBase+16+q*4+r   -> t+16..
    }
}

// ---------------------------------------------------------------------------
// Kernel 3 (v7 = R8 champion, VERBATIM): i8-dot4 scan, 64 blocks x 4 waves.
//
// Final model (fits R0-R9): step = 954 cy = ~424 issue (256 cy dots: 64
// v_dot4_i32_i8 at the uniform 4 cy/instr VALU issue rate, + ~170 tail/
// loads) + ~530 serial ring (LDS h round-trip ~120, trans/c chains ~200,
// shfl+barrier skew ~200). Configuration sweep complete:
//   waves/block 2/4/8 -> 4 best (R9/R8/R1); samples/block 1/2/16 -> 1 best
//   (R8/R3/R2); dot engine fdot2/pk_fma/MFMA/i8-dot4 -> dot4 best
//   (R7/R5/R2/R8); tail divergent/branchless -> branchless (R4).
// i4/dot8 would put 4-bit h into the recursion — numerically dead. No
// unexplored mechanism remains; this is the structural floor.
// ---------------------------------------------------------------------------
__global__ __launch_bounds__(256, 1) void lstm_scan_v7(
        const float* __restrict__ W,      // 256 x 512 f32 (rows 128.. = Wh)
        const f16* __restrict__ xpt,      // [64][512][2048] f16
        float* __restrict__ out) {        // ROWS x 128 f32
    __shared__ __align__(16) signed char hq[2][UNITS];   // 256 B

    const int tid  = threadIdx.x;
    const int b    = blockIdx.x;
    const int wave = tid >> 6;
    const int lane = tid & 63;
    const int half = lane >> 5;                 // 0: {i,f}  1: {o,g}
    const int cell = wave * 32 + (lane & 31);   // j in [0,128)
    const int c0   = cell + half * 256;         // i_j  or  o_j
    const int c1   = c0 + 128;                  // f_j  or  g_j

    // ---- per-column weight quantization (init only; W is 512 KiB, L2-hot)
    float mx0 = 1e-20f, mx1 = 1e-20f;
    for (int k = 0; k < 128; ++k) {
        mx0 = fmaxf(mx0, fabsf(W[(size_t)(IN_DIM + k) * GATES + c0]));
        mx1 = fmaxf(mx1, fabsf(W[(size_t)(IN_DIM + k) * GATES + c1]));
    }
    const float inv0 = 127.f / mx0, inv1 = 127.f / mx1;
    const float ms0 = mx0 * (1.f / (127.f * 127.f));
    const float ms1 = mx1 * (1.f / (127.f * 127.f));

    uint32_t wq0[32], wq1[32];
    #pragma unroll
    for (int d = 0; d < 32; ++d) {
        uint32_t p0 = 0, p1 = 0;
        #pragma unroll
        for (int j = 0; j < 4; ++j) {
            int q0 = (int)rintf(W[(size_t)(IN_DIM + 4 * d + j) * GATES + c0] * inv0);
            int q1 = (int)rintf(W[(size_t)(IN_DIM + 4 * d + j) * GATES + c1] * inv1);
            p0 |= (uint32_t)(q0 & 255) << (8 * j);
            p1 |= (uint32_t)(q1 & 255) << (8 * j);
        }
        wq0[d] = p0; wq1[d] = p1;
    }

    // branchless constants for the z1 nonlinearity (f: sigmoid, g: tanh)
    const float m1 = (half == 0) ? -1.44269504f : 2.8853900817779268f;
    const float A1 = (half == 0) ? 0.0f : 1.0f;
    const float B1 = (half == 0) ? 1.0f : -2.0f;

    float c = 1.0f;                                // reference: c0 = ones
    if (tid < UNITS) hq[0][tid] = 0;               // h0 = zeros

    // xp: per-lane column streams, 8 timesteps per 16B load
    const f16* xa = xpt + ((size_t)b * GATES + c0) * SEQ;
    const f16* xb = xpt + ((size_t)b * GATES + c1) * SEQ;
    f16x8 x0cur = *(const f16x8*)(xa);
    f16x8 x1cur = *(const f16x8*)(xb);
    f16x8 x0nxt = *(const f16x8*)(xa + 8);
    f16x8 x1nxt = *(const f16x8*)(xb + 8);
    __syncthreads();     // once, before the loop

    for (int w = 0; w < SEQ / 8; ++w) {
        // prefetch window w+2 (clamped; ~2 windows of cover)
        const int wn = (w + 2 < SEQ / 8) ? (w + 2) : (SEQ / 8 - 1);
        f16x8 x0pf = *(const f16x8*)(xa + (size_t)wn * 8);
        f16x8 x1pf = *(const f16x8*)(xb + (size_t)wn * 8);

        #pragma unroll
        for (int u = 0; u < 8; ++u) {
            const int cur = u & 1, nxt = cur ^ 1;   // w*8 even -> t&1 == u&1
            const float xc0 = (float)x0cur[u];      // static extract (no scratch)
            const float xc1 = (float)x1cur[u];

            // h broadcast: 8 x 16B LDS reads (128 i8), same address all lanes
            const uint4* hsrc = (const uint4*)(&hq[cur][0]);
            uint4 hb[8];
            #pragma unroll
            for (int i = 0; i < 8; ++i) hb[i] = hsrc[i];

            // dots: 64 v_dot4_i32_i8, 4 chains of 16, exact i32 accumulation
            int a00 = 0, a01 = 0, a10 = 0, a11 = 0;
            #pragma unroll
            for (int i = 0; i < 8; ++i) {
                const int d0 = (int)hb[i].x;
                const int d1 = (int)hb[i].y;
                const int d2 = (int)hb[i].z;
                const int d3 = (int)hb[i].w;
                const int k = 4 * i;
                if (i < 4) {
                    a00 = dot4(d0, wq0[k],     a00);
                    a10 = dot4(d0, wq1[k],     a10);
                    a00 = dot4(d1, wq0[k + 1], a00);
                    a10 = dot4(d1, wq1[k + 1], a10);
                    a00 = dot4(d2, wq0[k + 2], a00);
                    a10 = dot4(d2, wq1[k + 2], a10);
                    a00 = dot4(d3, wq0[k + 3], a00);
                    a10 = dot4(d3, wq1[k + 3], a10);
                } else {
                    a01 = dot4(d0, wq0[k],     a01);
                    a11 = dot4(d0, wq1[k],     a11);
                    a01 = dot4(d1, wq0[k + 1], a01);
                    a11 = dot4(d1, wq1[k + 1], a11);
                    a01 = dot4(d2, wq0[k + 2], a01);
                    a11 = dot4(d2, wq1[k + 2], a11);
                    a01 = dot4(d3, wq0[k + 3], a01);
                    a11 = dot4(d3, wq1[k + 3], a11);
                }
            }
            float z0 = fmaf((float)(a00 + a01), ms0, xc0);
            float z1 = fmaf((float)(a10 + a11), ms1, xc1);

            // nonlinearities (branchless z1) + exchange
            float s0 = sigmoid_f(z0);
            float e1 = __builtin_amdgcn_exp2f(m1 * z1);
            float s1 = B1 * __builtin_amdgcn_rcpf(1.0f + e1) + A1;
            float p0 = __shfl_xor(s0, 32, 64);   // partner's first  (o or i)
            float p1 = __shfl_xor(s1, 32, 64);   // partner's second (g or f)

            // both halves compute c,h via the SAME f32 op sequence:
            //   half0: s0=sig(i) s1=sig(f) p0=sig(o) p1=tanh(g)
            //   half1: s0=sig(o) s1=tanh(g) p0=sig(i) p1=sig(f)
            float fi = (half == 0) ? s1 : p1;    // sig(f)
            float ii = (half == 0) ? s0 : p0;    // sig(i)
            float gg = (half == 0) ? p1 : s1;    // tanh(g)
            float oo = (half == 0) ? p0 : s0;    // sig(o)
            c = fi * c + ii * gg;
            float h = oo * tanh_f(c);

            if (half == 0) {
                // |h| < 1 strictly -> rint(h*127) in [-127,127], no clamp
                hq[nxt][cell] = (signed char)(int)rintf(h * 127.f);
            } else {
                out[((size_t)b * SEQ + w * 8 + u) * UNITS + cell] = h;
            }
            lds_barrier();   // LDS-only ordering: loads/stores stay in flight
        }
        x0cur = x0nxt; x1cur = x1nxt;
        x0nxt = x0pf;  x1nxt = x1pf;
    }
}

// ---------------------------------------------------------------------------
// Fallback (workspace too small): fused 4-wave scan, weights register-resident.
// ---------------------------------------------------------------------------
__global__ __launch_bounds__(256, 1) void lstm_scan_fused(
        const float* __restrict__ W,      // 256 x 512 f32
        const float* __restrict__ bias,   // 512 f32
        const float* __restrict__ data,   // ROWS x 128 f32
        float* __restrict__ out) {        // ROWS x 128 f32
    __shared__ __align__(16) f16 h_lds[2][UNITS];
    __shared__ __align__(16) f16 x_lds[2][UNITS];

    const int tid  = threadIdx.x;
    const int b    = blockIdx.x;
    const int wave = tid >> 6;
    const int lane = tid & 63;
    const int half = lane >> 5;
    const int cell = wave * 32 + (lane & 31);
    const int c0   = cell + half * 256;
    const int c1   = c0 + 128;

    f16x2 wh0[64], wh1[64];
    #pragma unroll
    for (int k = 0; k < 64; ++k) {
        wh0[k] = f16x2{(f16)W[(size_t)(IN_DIM + 2 * k) * GATES + c0],
                       (f16)W[(size_t)(IN_DIM + 2 * k + 1) * GATES + c0]};
        wh1[k] = f16x2{(f16)W[(size_t)(IN_DIM + 2 * k) * GATES + c1],
                       (f16)W[(size_t)(IN_DIM + 2 * k + 1) * GATES + c1]};
    }
    f16x2 wxa[64], wxb[64];
    #pragma unroll
    for (int k = 0; k < 64; ++k) {
        wxa[k] = f16x2{(f16)W[(size_t)(2 * k) * GATES + c0],
                       (f16)W[(size_t)(2 * k + 1) * GATES + c0]};
        wxb[k] = f16x2{(f16)W[(size_t)(2 * k) * GATES + c1],
                       (f16)W[(size_t)(2 * k + 1) * GATES + c1]};
    }
    float bb0 = bias[c0];
    float bb1 = bias[c1];

    float c = 1.0f;
    if (tid < UNITS) h_lds[0][tid] = (f16)0.f;
    if (tid < UNITS)
        x_lds[0][tid] = (f16)data[(size_t)b * SEQ * IN_DIM + tid];
    __syncthreads();

    for (int t = 0; t < SEQ; ++t) {
        const int cur = t & 1, nxt = cur ^ 1;
        float a00 = bb0, a01 = 0.f, a10 = bb1, a11 = 0.f;

        {
            const uint4* xsrc = (const uint4*)(&x_lds[cur][0]);
            uint4 xb[16];
            #pragma unroll
            for (int i = 0; i < 16; ++i) xb[i] = xsrc[i];
            #pragma unroll
            for (int i = 0; i < 16; ++i) {
                f16x2 p0 = __builtin_bit_cast(f16x2, xb[i].x);
                f16x2 p1 = __builtin_bit_cast(f16x2, xb[i].y);
                f16x2 p2 = __builtin_bit_cast(f16x2, xb[i].z);
                f16x2 p3 = __builtin_bit_cast(f16x2, xb[i].w);
                const int k = 4 * i;
                if (i < 8) {
                    a00 = __builtin_amdgcn_fdot2(p0, wxa[k],     a00, false);
                    a10 = __builtin_amdgcn_fdot2(p0, wxb[k],     a10, false);
                    a00 = __builtin_amdgcn_fdot2(p1, wxa[k + 1], a00, false);
                    a10 = __builtin_amdgcn_fdot2(p1, wxb[k + 1], a10, false);
                    a00 = __builtin_amdgcn_fdot2(p2, wxa[k + 2], a00, false);
                    a10 = __builtin_amdgcn_fdot2(p2, wxb[k + 2], a10, false);
                    a00 = __builtin_amdgcn_fdot2(p3, wxa[k + 3], a00, false);
                    a10 = __builtin_amdgcn_fdot2(p3, wxb[k + 3], a10, false);
                } else {
                    a01 = __builtin_amdgcn_fdot2(p0, wxa[k],     a01, false);
                    a11 = __builtin_amdgcn_fdot2(p0, wxb[k],     a11, false);
                    a01 = __builtin_amdgcn_fdot2(p1, wxa[k + 1], a01, false);
                    a11 = __builtin_amdgcn_fdot2(p1, wxb[k + 1], a11, false);
                    a01 = __builtin_amdgcn_fdot2(p2, wxa[k + 2], a01, false);
                    a11 = __builtin_amdgcn_fdot2(p2, wxb[k + 2], a11, false);
                    a01 = __builtin_amdgcn_fdot2(p3, wxa[k + 3], a01, false);
                    a11 = __builtin_amdgcn_fdot2(p3, wxb[k + 3], a11, false);
                }
            }
        }
        {
            const uint4* hsrc = (const uint4*)(&h_lds[cur][0]);
            uint4 hb[16];
            #pragma unroll
            for (int i = 0; i < 16; ++i) hb[i] = hsrc[i];
            #pragma unroll
            for (int i = 0; i < 16; ++i) {
                f16x2 p0 = __builtin_bit_cast(f16x2, hb[i].x);
                f16x2 p1 = __builtin_bit_cast(f16x2, hb[i].y);
                f16x2 p2 = __builtin_bit_cast(f16x2, hb[i].z);
                f16x2 p3 = __builtin_bit_cast(f16x2, hb[i].w);
                const int k = 4 * i;
                if (i < 8) {
                    a00 = __builtin_amdgcn_fdot2(p0, wh0[k],     a00, false);
                    a10 = __builtin_amdgcn_fdot2(p0, wh1[k],     a10, false);
                    a00 = __builtin_amdgcn_fdot2(p1, wh0[k + 1], a00, false);
                    a10 = __builtin_amdgcn_fdot2(p1, wh1[k + 1], a10, false);
                    a00 = __builtin_amdgcn_fdot2(p2, wh0[k + 2], a00, false);
                    a10 = __builtin_amdgcn_fdot2(p2, wh1[k + 2], a10, false);
                    a00 = __builtin_amdgcn_fdot2(p3, wh0[k + 3], a00, false);
                    a10 = __builtin_amdgcn_fdot2(p3, wh1[k + 3], a10, false);
                } else {
                    a01 = __builtin_amdgcn_fdot2(p0, wh0[k],     a01, false);
                    a11 = __builtin_amdgcn_fdot2(p0, wh1[k],     a11, false);
                    a01 = __builtin_amdgcn_fdot2(p1, wh0[k + 1], a01, false);
                    a11 = __builtin_amdgcn_fdot2(p1, wh1[k + 1], a11, false);
                    a01 = __builtin_amdgcn_fdot2(p2, wh0[k + 2], a01, false);
                    a11 = __builtin_amdgcn_fdot2(p2, wh1[k + 2], a11, false);
                    a01 = __builtin_amdgcn_fdot2(p3, wh0[k + 3], a01, false);
                    a11 = __builtin_amdgcn_fdot2(p3, wh1[k + 3], a11, false);
                }
            }
        }
        float z0 = a00 + a01, z1 = a10 + a11;

        float s0 = sigmoid_f(z0);
        float s1 = (half == 0) ? sigmoid_f(z1) : tanh_f(z1);
        float p0 = __shfl_xor(s0, 32, 64);
        float p1 = __shfl_xor(s1, 32, 64);

        if (half == 0) {
            c = s1 * c + s0 * p1;
            float h = p0 * tanh_f(c);
            h_lds[nxt][cell] = (f16)h;
            out[((size_t)b * SEQ + t) * UNITS + cell] = h;
        }
        if (tid < UNITS) {
            int t1 = (t + 1 < SEQ) ? (t + 1) : t;
            x_lds[nxt][tid] = (f16)data[(size_t)b * SEQ * IN_DIM
                                        + (size_t)t1 * IN_DIM + tid];
        }
        lds_barrier();
    }
}

// ---------------------------------------------------------------------------
extern "C" void kernel_launch(void* const* d_in, const int* in_sizes, int n_in,
                              void* d_out, int out_size, void* d_ws, size_t ws_size,
                              hipStream_t stream) {
    const float* data = (const float*)d_in[0];   // f32 (64,2048,128)
    const float* W    = (const float*)d_in[1];   // f32 (256,512)
    const float* bias = (const float*)d_in[2];   // f32 (512,)
    float* out = (float*)d_out;                  // f32 (64,2048,128)

    const size_t wxt_bytes = (size_t)GATES * IN_DIM * sizeof(f16);  // 128 KiB
    const size_t xp_bytes  = (size_t)ROWS * GATES * sizeof(f16);    // 128 MiB
    if (ws_size >= wxt_bytes + xp_bytes) {
        f16* WxT = (f16*)d_ws;
        f16* xp  = (f16*)((char*)d_ws + wxt_bytes);
        hipLaunchKernelGGL(wxt_kernel, dim3(256), dim3(256), 0, stream, W, WxT);
        hipLaunchKernelGGL(xp_gemm, dim3(ROWS / 128), dim3(256), 0, stream,
                           data, WxT, bias, xp);
        hipLaunchKernelGGL(lstm_scan_v7, dim3(BATCH), dim3(256), 0, stream,
                           W, xp, out);
    } else {
        // Workspace too small: fused fallback (all weights register-resident).
        hipLaunchKernelGGL(lstm_scan_fused, dim3(BATCH), dim3(256), 0, stream,
                           W, bias, data, out);
    }
}